// Round 1
// baseline (16.394 us; speedup 1.0000x reference)
//
#include <hip/hip_runtime.h>
#include <math.h>

// Problem constants (from setup_inputs): bs=2, Q=256, C=16, P=20, T=256
#define BS   2
#define NQ   256
#define NCLS 16
#define NP   20
#define NT   256
#define NN   (BS * NQ)   // 512 predictions
#define FEPS 1e-6f

// One block per prediction n (512 blocks), one thread per target t (256 threads).
// Pred polyline + logits staged in LDS (uniform broadcast reads).
// Target polyline + per-q running mins live in registers.
__global__ __launch_bounds__(NT) void matcher_cost_kernel(
    const float* __restrict__ logits,   // [NN, NCLS]
    const float* __restrict__ ppoly,    // [NN, NP, 2]
    const int*   __restrict__ tlabels,  // [NT]
    const float* __restrict__ tpoly,    // [NT, NP, 2]
    float*       __restrict__ out)      // [NN, NT]
{
    const int n = blockIdx.x;
    const int t = threadIdx.x;

    __shared__ float s_px[NP];
    __shared__ float s_py[NP];
    __shared__ float s_logit[NCLS];

    // Stage pred polyline (40 floats) and logits (16 floats) into LDS.
    if (t < NP * 2) {
        float v = ppoly[n * NP * 2 + t];
        if (t & 1) s_py[t >> 1] = v;
        else       s_px[t >> 1] = v;
    }
    if (t < NCLS) s_logit[t] = logits[n * NCLS + t];
    __syncthreads();

    // --- load this thread's target polyline into registers (40 floats) ---
    float tx[NP], ty[NP];
    #pragma unroll
    for (int p = 0; p < NP; ++p) {
        float2 v = *reinterpret_cast<const float2*>(&tpoly[(t * NP + p) * 2]);
        tx[p] = v.x;
        ty[p] = v.y;
    }

    // --- classification cost: -softmax(logits[n])[label[t]] ---
    // Redundant per-thread softmax over 16 uniform LDS values (broadcast, cheap).
    float mx = s_logit[0];
    #pragma unroll
    for (int c = 1; c < NCLS; ++c) mx = fmaxf(mx, s_logit[c]);
    float denom = 0.f;
    #pragma unroll
    for (int c = 0; c < NCLS; ++c) denom += __expf(s_logit[c] - mx);
    const int lbl = tlabels[t];
    const float cost_class = -__expf(s_logit[lbl] - mx) / denom;

    // --- polyline cost: bidirectional avg-of-min L1 (Chamfer-style) ---
    float m2[NP];
    #pragma unroll
    for (int q = 0; q < NP; ++q) m2[q] = 1e30f;

    float sum1 = 0.f;
    #pragma unroll
    for (int p = 0; p < NP; ++p) {
        const float px = s_px[p];   // uniform LDS broadcast
        const float py = s_py[p];
        float m1 = 1e30f;
        #pragma unroll
        for (int q = 0; q < NP; ++q) {
            const float d = fabsf(px - tx[q]) + fabsf(py - ty[q]);
            m1    = fminf(m1, d);
            m2[q] = fminf(m2[q], d);
        }
        sum1 += m1;
    }
    float sum2 = 0.f;
    #pragma unroll
    for (int q = 0; q < NP; ++q) sum2 += m2[q];
    const float cost_poly = (sum1 + sum2) * (0.5f / (float)NP);

    // --- direction cost: 1 - cos(start->end) ---
    float pdx = s_px[NP - 1] - s_px[0];
    float pdy = s_py[NP - 1] - s_py[0];
    const float pn = sqrtf(pdx * pdx + pdy * pdy) + FEPS;
    pdx /= pn; pdy /= pn;

    float gdx = tx[NP - 1] - tx[0];
    float gdy = ty[NP - 1] - ty[0];
    const float gn = sqrtf(gdx * gdx + gdy * gdy) + FEPS;
    gdx /= gn; gdy /= gn;

    const float cost_dir = 1.f - (pdx * gdx + pdy * gdy);

    out[n * NT + t] = cost_class + cost_poly + cost_dir;
}

extern "C" void kernel_launch(void* const* d_in, const int* in_sizes, int n_in,
                              void* d_out, int out_size, void* d_ws, size_t ws_size,
                              hipStream_t stream) {
    const float* logits  = (const float*)d_in[0];  // [2,256,16]
    const float* ppoly   = (const float*)d_in[1];  // [2,256,20,2]
    const int*   tlabels = (const int*)d_in[2];    // [256]
    const float* tpoly   = (const float*)d_in[3];  // [256,20,2]
    float*       out     = (float*)d_out;          // [2,256,256]

    matcher_cost_kernel<<<dim3(NN), dim3(NT), 0, stream>>>(
        logits, ppoly, tlabels, tpoly, out);
}

// Round 2
// 12.524 us; speedup vs baseline: 1.3091x; 1.3091x over previous
//
#include <hip/hip_runtime.h>
#include <math.h>

// Problem constants (from setup_inputs): bs=2, Q=256, C=16, P=20, T=256
#define BS   2
#define NQ   256
#define NCLS 16
#define NP   20
#define NT   256
#define NN   (BS * NQ)   // 512 predictions
#define FEPS 1e-6f
#define PHALF (NP / 2)

// One block per prediction n (512 blocks), 512 threads: lane pair (2t, 2t+1)
// handles target t; z = tid&1 owns half the p-loop. Cross-lane combine via
// __shfl_xor(.,1). This doubles wave count (4 waves/SIMD) vs the R1 kernel,
// halving the per-thread latency chain.
__global__ __launch_bounds__(2 * NT) void matcher_cost_kernel(
    const float* __restrict__ logits,   // [NN, NCLS]
    const float* __restrict__ ppoly,    // [NN, NP, 2]
    const int*   __restrict__ tlabels,  // [NT]
    const float* __restrict__ tpoly,    // [NT, NP, 2]
    float*       __restrict__ out)      // [NN, NT]
{
    const int n   = blockIdx.x;
    const int tid = threadIdx.x;   // 0..511
    const int t   = tid >> 1;      // target 0..255
    const int z   = tid & 1;       // p-half: 0 -> p[0,10), 1 -> p[10,20)

    __shared__ float s_px[NP];
    __shared__ float s_py[NP];
    __shared__ float s_logit[NCLS];

    // Stage pred polyline (40 floats) and logits (16 floats) into LDS.
    if (tid < NP * 2) {
        float v = ppoly[n * NP * 2 + tid];
        if (tid & 1) s_py[tid >> 1] = v;
        else         s_px[tid >> 1] = v;
    }
    if (tid < NCLS) s_logit[tid] = logits[n * NCLS + tid];
    __syncthreads();

    // --- load this thread's target polyline into registers (40 floats, float4) ---
    float tx[NP], ty[NP];
    #pragma unroll
    for (int p = 0; p < NP; p += 2) {
        float4 v = *reinterpret_cast<const float4*>(&tpoly[(t * NP + p) * 2]);
        tx[p]     = v.x;  ty[p]     = v.y;
        tx[p + 1] = v.z;  ty[p + 1] = v.w;
    }

    // --- classification cost: -softmax(logits[n])[label[t]] ---
    float mx = s_logit[0];
    #pragma unroll
    for (int c = 1; c < NCLS; ++c) mx = fmaxf(mx, s_logit[c]);
    float denom = 0.f;
    #pragma unroll
    for (int c = 0; c < NCLS; ++c) denom += __expf(s_logit[c] - mx);
    const int lbl = tlabels[t];
    const float cost_class = -__expf(s_logit[lbl] - mx) / denom;

    // --- polyline cost: bidirectional avg-of-min L1, p-loop split across z ---
    float m2[NP];
    #pragma unroll
    for (int q = 0; q < NP; ++q) m2[q] = 1e30f;

    float sum1 = 0.f;
    const int p0 = z * PHALF;
    #pragma unroll
    for (int pp = 0; pp < PHALF; ++pp) {
        const float px = s_px[p0 + pp];   // 2 distinct LDS addrs/wave: free
        const float py = s_py[p0 + pp];
        float m1 = 1e30f;
        #pragma unroll
        for (int q = 0; q < NP; ++q) {
            const float d = fabsf(px - tx[q]) + fabsf(py - ty[q]);
            m1    = fminf(m1, d);
            m2[q] = fminf(m2[q], d);
        }
        sum1 += m1;
    }
    // combine the two p-halves across the lane pair
    sum1 += __shfl_xor(sum1, 1);
    float sum2 = 0.f;
    #pragma unroll
    for (int q = 0; q < NP; ++q)
        sum2 += fminf(m2[q], __shfl_xor(m2[q], 1));

    const float cost_poly = (sum1 + sum2) * (0.5f / (float)NP);

    // --- direction cost: 1 - cos(start->end) ---
    float pdx = s_px[NP - 1] - s_px[0];
    float pdy = s_py[NP - 1] - s_py[0];
    const float pn = sqrtf(pdx * pdx + pdy * pdy) + FEPS;
    pdx /= pn; pdy /= pn;

    float gdx = tx[NP - 1] - tx[0];
    float gdy = ty[NP - 1] - ty[0];
    const float gn = sqrtf(gdx * gdx + gdy * gdy) + FEPS;
    gdx /= gn; gdy /= gn;

    const float cost_dir = 1.f - (pdx * gdx + pdy * gdy);

    if (z == 0) out[n * NT + t] = cost_class + cost_poly + cost_dir;
}

extern "C" void kernel_launch(void* const* d_in, const int* in_sizes, int n_in,
                              void* d_out, int out_size, void* d_ws, size_t ws_size,
                              hipStream_t stream) {
    const float* logits  = (const float*)d_in[0];  // [2,256,16]
    const float* ppoly   = (const float*)d_in[1];  // [2,256,20,2]
    const int*   tlabels = (const int*)d_in[2];    // [256]
    const float* tpoly   = (const float*)d_in[3];  // [256,20,2]
    float*       out     = (float*)d_out;          // [2,256,256]

    matcher_cost_kernel<<<dim3(NN), dim3(2 * NT), 0, stream>>>(
        logits, ppoly, tlabels, tpoly, out);
}